// Round 8
// baseline (450.112 us; speedup 1.0000x reference)
//
#include <hip/hip_runtime.h>

// ---------------------------------------------------------------- constants
#define TTOK 32768
#define DM   256
#define NF   1024
#define KMAX 32

typedef __attribute__((ext_vector_type(8))) unsigned short ushort8;
typedef __attribute__((ext_vector_type(8))) __bf16 bf16x8;
typedef __attribute__((ext_vector_type(4))) float floatx4;
typedef __attribute__((ext_vector_type(2))) float f32x2;

// workspace offsets (all 256B aligned)
constexpr size_t O_SLOT = 0;                                   // 1 uint (max|Wt|)
constexpr size_t O_S    = 256;                                 // 1024 f32 sigmoid(alpha)
constexpr size_t O_WCT  = O_S    + 4096;                       // Wc^T  [1024][256] bf16
constexpr size_t O_WGT  = O_WCT  + (size_t)NF*DM*2;            // Wg^T  [1024][256] bf16
constexpr size_t O_WDT  = O_WGT  + (size_t)NF*DM*2;            // Wd^T  [256][1024] bf16
constexpr size_t O_WTT  = O_WDT  + (size_t)DM*NF*2;            // Wt^T  [256][1024] f32
constexpr size_t O_XBF  = O_WTT  + (size_t)DM*NF*4;            // x bf16 [T][256]
constexpr size_t O_CNT  = O_XBF  + (size_t)TTOK*DM*2;          // counts [T]
constexpr size_t O_CIDX = O_CNT  + (size_t)TTOK*4;             // cand d (raw) [T][KMAX]
constexpr size_t O_CVAL = O_CIDX + (size_t)TTOK*KMAX*4;        // cand val [T][KMAX]
constexpr size_t O_FUSD = O_CVAL + (size_t)TTOK*KMAX*4;        // fused bf16 [T][1024]

__device__ __forceinline__ float bf2f(unsigned short u) {
    union { unsigned int i; float f; } c; c.i = ((unsigned int)u) << 16; return c.f;
}
__device__ __forceinline__ unsigned short f2bf(float v) {
    union { float f; unsigned int i; } c; c.f = v;
    unsigned int b = c.i;
    return (unsigned short)((b + 0x7FFFu + ((b >> 16) & 1u)) >> 16);
}
__device__ __forceinline__ float sigm(float z) { return 1.0f / (1.0f + __expf(-z)); }
// tanh-gelu: max |diff| vs exact erf-gelu ~3e-3, far under 0.266 tolerance
__device__ __forceinline__ float gelu_f(float x) {
    return x * sigm(1.59576912f * (x + 0.044715f * x * x * x));
}
// async global->LDS, 16B per lane; lds dest = wave-uniform base + lane*16 [m97/m104]
__device__ __forceinline__ void g2lds16(const unsigned short* g, unsigned short* l) {
    __builtin_amdgcn_global_load_lds((const __attribute__((address_space(1))) unsigned int*)g,
                                     (__attribute__((address_space(3))) unsigned int*)l, 16, 0, 0);
}

// ------------------------------------------------- kernel 1: pack weights
__global__ void pack_kernel(const float* __restrict__ Wt, const float* __restrict__ alpha,
                            const float* __restrict__ Wc, const float* __restrict__ Wg,
                            const float* __restrict__ Wd,
                            unsigned short* __restrict__ Wct, unsigned short* __restrict__ Wgt,
                            unsigned short* __restrict__ WdT, float* __restrict__ WtT,
                            float* __restrict__ s, unsigned int* __restrict__ slot) {
    int e = blockIdx.x * 256 + threadIdx.x;
    if (e == 0) *slot = 0u;
    { int f = e >> 8, k = e & 255;           // Wc/Wg are [256][1024]
      Wct[e] = f2bf(Wc[k * NF + f]);
      Wgt[e] = f2bf(Wg[k * NF + f]); }
    { int n = e >> 10, k = e & 1023;         // Wd is [1024][256]
      WdT[e] = f2bf(Wd[k * DM + n]); }
    { int d = e >> 10, f = e & 1023;         // Wt is [1024][256]
      WtT[e] = Wt[f * DM + d]; }
    if (e < NF) s[e] = sigm(alpha[e]);
}

// ------------------------------------------------- kernel 2: max|Wt| reduce
__global__ void minmax_kernel(const float* __restrict__ Wt, unsigned int* __restrict__ slot) {
    int g = blockIdx.x * 256 + threadIdx.x;
    float lm = 0.0f;
    for (int i = g; i < NF * DM; i += 128 * 256) lm = fmaxf(lm, fabsf(Wt[i]));
    #pragma unroll
    for (int o = 32; o > 0; o >>= 1) lm = fmaxf(lm, __shfl_xor(lm, o));
    if ((threadIdx.x & 63) == 0) atomicMax(slot, __float_as_uint(lm)); // |w|>=0: uint order ok
}

// ------------------------------------------------- kernel 3: candidates + x->bf16
// wave per token (r8: was block per token -> 32768 tiny blocks). Ballot
// compaction, no LDS, no atomics. lane covers 4 d's via float4.
__global__ void cand_kernel(const float* __restrict__ x, const unsigned int* __restrict__ slot,
                            unsigned short* __restrict__ xbf, int* __restrict__ counts,
                            int* __restrict__ cidx, float* __restrict__ cval) {
    const int wave = threadIdx.x >> 6, lane = threadIdx.x & 63;
    const int i = blockIdx.x * 4 + wave;
    float4 xv = *(const float4*)(x + (size_t)i * DM + lane * 4);
    ushort4 xb;
    xb.x = f2bf(xv.x); xb.y = f2bf(xv.y); xb.z = f2bf(xv.z); xb.w = f2bf(xv.w);
    *(ushort4*)(xbf + (size_t)i * DM + lane * 4) = xb;
    float m = fmaxf(fmaxf(xv.x, xv.y), fmaxf(xv.z, xv.w));
    #pragma unroll
    for (int o = 32; o > 0; o >>= 1) m = fmaxf(m, __shfl_xor(m, o));
    float delta = 2.0f * __uint_as_float(*slot);   // >= Wmax - Wmin : exact exclusion bound
    float thr = m - delta;
    unsigned long long ltmask = (lane == 63) ? ~0ULL >> 1 : ((1ULL << (lane + (lane != 63))) - 1);
    ltmask = (1ULL << lane) - 1;   // lanes below me
    int base = 0;
    float vv[4] = { xv.x, xv.y, xv.z, xv.w };
    #pragma unroll
    for (int j = 0; j < 4; j++) {
        bool p = vv[j] >= thr;
        unsigned long long mk = __ballot(p);
        int pos = base + (int)__popcll(mk & ltmask);
        if (p && pos < KMAX) {
            cidx[(size_t)i * KMAX + pos] = lane * 4 + j;
            cval[(size_t)i * KMAX + pos] = vv[j];
        }
        base += (int)__popcll(mk);
    }
    if (lane == 0) counts[i] = base;
}

// ------------------------------------------------- kernel 4: fused GEMM1
// (x@Wc, x@Wg) MFMA + tropical max-plus + convex/concave + gate blend.
// 128x128 tile, BK=32, 512 thr (8 waves 2Mx4F, wave 64x32 dual-output).
// r8 structure (r7 was VALU-bound at 78%):
//  - z-phase: wave-per-token. Candidate loop is WAVE-UNIFORM & EXACT per token
//    (r7 ran each wave to max-count over its 16 m-rows: ~2x wasted iters) with
//    coalesced Wt row reads (single base per k, 64B segments). z -> LDS as
//    bf16 (f, f+16) pairs (r4-proven quantization).
//  - epilogue: the (f,f+16) pair == (ni0,ni1) -> packed <2 x float> math via
//    __builtin_elementwise_* -> v_pk_fma/max/min_f32. Params staged as float2
//    pairs in LDS (stride 74 words: 16 lr lanes hit 16 distinct banks).
//  - obuf half-tile (LDS total 70144 = 2 blocks/CU), proven coalesced store.
#define LDSS 32   // ushorts per LDS row, no pad (wave-uniform-base DMA, m104)
#define KPAD 33
#define OSTR 136
__global__ __launch_bounds__(512, 4) void gemm1_kernel(
    const unsigned short* __restrict__ A,   // xbf [T][256]
    const unsigned short* __restrict__ Bct, // [1024][256]
    const unsigned short* __restrict__ Bgt, // [1024][256]
    const float* __restrict__ bc, const float* __restrict__ bg,
    const int* __restrict__ counts, const int* __restrict__ cidx,
    const float* __restrict__ cval, const float* __restrict__ x,
    const float* __restrict__ WtT, const float* __restrict__ bt,
    const float* __restrict__ slx, const float* __restrict__ ofx,
    const float* __restrict__ slc, const float* __restrict__ ofc,
    const float* __restrict__ s, unsigned short* __restrict__ fused) {
    __shared__ __align__(16) char smem[70144];
    unsigned short* As  = (unsigned short*)smem;            // [0, 8K)       K-loop
    unsigned short* Bcs = As + 4096;                        // [8K, 16K)     K-loop
    unsigned short* Bgs = As + 8192;                        // [16K, 24K)    K-loop
    unsigned int* zbuf = (unsigned int*)smem;               // [0, 33280)    post K-loop
    int* sCnt = (int*)(smem + 33280);                       // 512B
    int* sOV  = (int*)(smem + 33792);                       // 16896 (z-phase)
    float* par2 = (float*)(smem + 33792);                   // 18944 (epilogue, overlays sOV)
    unsigned short* obuf = (unsigned short*)(smem + 52736); // 17408 (64x136)
    const int t = threadIdx.x;
    // XCD-aware swizzle: 8 bf-siblings of one bm consecutive within an XCD
    const int b = blockIdx.x;
    const int xcd = b & 7, j = b >> 3;
    const int bf = j & 7;
    const int bm = (j >> 3) * 8 + xcd;
    const int wave = t >> 6, lane = t & 63;
    const int wm = wave & 1, wn = wave >> 1;
    const int lr = lane & 15, quad = lane >> 4;
    const int srow = wave * 16 + (lane >> 2), scol = (lane & 3) << 3;
    const unsigned short* gA = A   + (size_t)(bm * 128 + srow) * DM + scol;
    const unsigned short* gC = Bct + (size_t)(bf * 128 + srow) * DM + scol;
    const unsigned short* gG = Bgt + (size_t)(bf * 128 + srow) * DM + scol;
    unsigned short* lA = &As[wave * 16 * LDSS];
    unsigned short* lC = &Bcs[wave * 16 * LDSS];
    unsigned short* lG = &Bgs[wave * 16 * LDSS];

    if (t < 128) sCnt[t] = counts[bm * 128 + t];

    floatx4 accc[4][2], accg[4][2];
    #pragma unroll
    for (int i = 0; i < 4; i++)
        #pragma unroll
        for (int jj = 0; jj < 2; jj++) { accc[i][jj] = (floatx4)0.0f; accg[i][jj] = (floatx4)0.0f; }

    for (int k0 = 0; k0 < DM; k0 += 32) {
        __syncthreads();            // covers sCnt stage (1st iter) + prior ds_reads
        g2lds16(gA + k0, lA);
        g2lds16(gC + k0, lC);
        g2lds16(gG + k0, lG);
        __syncthreads();
        bf16x8 af[4], bcf[2], bgf[2];
        #pragma unroll
        for (int mi = 0; mi < 4; mi++)
            af[mi] = *(const bf16x8*)&As[(wm * 64 + mi * 16 + lr) * LDSS + quad * 8];
        #pragma unroll
        for (int ni = 0; ni < 2; ni++) {
            bcf[ni] = *(const bf16x8*)&Bcs[(wn * 32 + ni * 16 + lr) * LDSS + quad * 8];
            bgf[ni] = *(const bf16x8*)&Bgs[(wn * 32 + ni * 16 + lr) * LDSS + quad * 8];
        }
        #pragma unroll
        for (int mi = 0; mi < 4; mi++)
            #pragma unroll
            for (int ni = 0; ni < 2; ni++) {
                accc[mi][ni] = __builtin_amdgcn_mfma_f32_16x16x32_bf16(af[mi], bcf[ni], accc[mi][ni], 0, 0, 0);
                accg[mi][ni] = __builtin_amdgcn_mfma_f32_16x16x32_bf16(af[mi], bgf[ni], accg[mi][ni], 0, 0, 0);
            }
    }
    __syncthreads();   // staging bufs dead

    // ---- stage packed candidate meta: (bf16(val)<<16) | d
    const int PADV = (int)(((unsigned int)f2bf(-1e30f)) << 16);
    for (int e = t; e < 128 * KMAX; e += 512) {
        int m = e >> 5, k = e & 31;
        int c = sCnt[m];
        int pk = PADV;
        if (k < (c < KMAX ? c : KMAX)) {
            int d  = cidx[(size_t)(bm * 128 + m) * KMAX + k];
            float v = cval[(size_t)(bm * 128 + m) * KMAX + k];
            pk = (int)(((unsigned int)f2bf(v)) << 16) | d;
        }
        sOV[m * KPAD + k] = pk;
    }
    __syncthreads();

    // ---- z-phase: wave per token, uniform exact k-loop, coalesced Wt reads
    {
        const int fa = bf * 128 + ((lane >> 4) * 32) + (lane & 15);  // pair = (fa, fa+16)
        for (int mm = 0; mm < 16; mm++) {
            int m = wave * 16 + mm;
            int c = sCnt[m];
            float za = -1e30f, zb = -1e30f;
            if (c <= KMAX) {
                int k = 0;
                for (; k + 1 < c; k += 2) {
                    int p0 = sOV[m * KPAD + k];
                    int p1 = sOV[m * KPAD + k + 1];
                    const float* r0 = WtT + ((p0 & 0xFFFF) << 10) + fa;
                    const float* r1 = WtT + ((p1 & 0xFFFF) << 10) + fa;
                    float w0a = r0[0], w0b = r0[16];
                    float w1a = r1[0], w1b = r1[16];
                    float v0 = __int_as_float(p0 & 0xFFFF0000);
                    float v1 = __int_as_float(p1 & 0xFFFF0000);
                    za = fmaxf(za, v0 + w0a); zb = fmaxf(zb, v0 + w0b);
                    za = fmaxf(za, v1 + w1a); zb = fmaxf(zb, v1 + w1b);
                }
                if (k < c) {
                    int p0 = sOV[m * KPAD + k];
                    const float* r0 = WtT + ((p0 & 0xFFFF) << 10) + fa;
                    float v0 = __int_as_float(p0 & 0xFFFF0000);
                    za = fmaxf(za, v0 + r0[0]); zb = fmaxf(zb, v0 + r0[16]);
                }
            } else {  // exact fallback (never expected)
                const float* xr = x + (size_t)(bm * 128 + m) * DM;
                for (int d = 0; d < DM; d++) {
                    float xv = xr[d];
                    const float* r0 = WtT + d * NF + fa;
                    za = fmaxf(za, xv + r0[0]); zb = fmaxf(zb, xv + r0[16]);
                }
            }
            zbuf[m * 65 + lane] = ((unsigned int)f2bf(zb) << 16) | f2bf(za);
        }
    }
    __syncthreads();

    // ---- stage params as (f, f+16) float2 pairs; stride 74 words
    // idx: 0-7 slx, 8-15 ofx, 16-23 slc, 24-31 ofc, 32 bt, 33 s, 34 bc, 35 bg
    for (int e = t; e < 64 * 36; e += 512) {
        int jl2 = e / 36, idx = e % 36;
        int f0 = bf * 128 + ((jl2 >> 4) * 32) + (jl2 & 15);
        float v0, v1;
        if (idx < 8)       { v0 = slx[f0 * 8 + idx];      v1 = slx[(f0 + 16) * 8 + idx]; }
        else if (idx < 16) { v0 = ofx[f0 * 8 + idx - 8];  v1 = ofx[(f0 + 16) * 8 + idx - 8]; }
        else if (idx < 24) { v0 = slc[f0 * 8 + idx - 16]; v1 = slc[(f0 + 16) * 8 + idx - 16]; }
        else if (idx < 32) { v0 = ofc[f0 * 8 + idx - 24]; v1 = ofc[(f0 + 16) * 8 + idx - 24]; }
        else if (idx == 32){ v0 = bt[f0]; v1 = bt[f0 + 16]; }
        else if (idx == 33){ v0 = s[f0];  v1 = s[f0 + 16]; }
        else if (idx == 34){ v0 = bc[f0]; v1 = bc[f0 + 16]; }
        else               { v0 = bg[f0]; v1 = bg[f0 + 16]; }
        par2[jl2 * 74 + idx * 2]     = v0;
        par2[jl2 * 74 + idx * 2 + 1] = v1;
    }
    __syncthreads();

    // ---- packed epilogue ----
    const int jl = wn * 16 + lr;
    const float* pp = par2 + jl * 74;
    f32x2 bt2 = *(const f32x2*)(pp + 64);
    f32x2 s2  = *(const f32x2*)(pp + 66);
    f32x2 bc2 = *(const f32x2*)(pp + 68);
    f32x2 bg2 = *(const f32x2*)(pp + 70);
    for (int h = 0; h < 2; h++) {
        #pragma unroll
        for (int mi2 = 0; mi2 < 2; mi2++) {
            const int mi = h * 2 + mi2;
            const int mb = wm * 64 + mi * 16 + quad * 4;
            f32x2 z2[4];
            #pragma unroll
            for (int r = 0; r < 4; r++) {
                unsigned int u = zbuf[(mb + r) * 65 + jl];
                f32x2 zz;
                zz.x = bf2f((unsigned short)(u & 0xFFFF));
                zz.y = bf2f((unsigned short)(u >> 16));
                z2[r] = zz + bt2;
            }
            f32x2 cvx[4], ccv[4];
            #pragma unroll
            for (int r = 0; r < 4; r++)
                cvx[r] = __builtin_elementwise_fma(z2[r], *(const f32x2*)(pp + 0), *(const f32x2*)(pp + 16));
            #pragma unroll
            for (int jj = 1; jj < 8; jj++) {
                f32x2 sl = *(const f32x2*)(pp + 2 * jj);
                f32x2 of = *(const f32x2*)(pp + 16 + 2 * jj);
                #pragma unroll
                for (int r = 0; r < 4; r++)
                    cvx[r] = __builtin_elementwise_max(cvx[r], __builtin_elementwise_fma(z2[r], sl, of));
            }
            #pragma unroll
            for (int r = 0; r < 4; r++)
                ccv[r] = __builtin_elementwise_fma(z2[r], *(const f32x2*)(pp + 32), *(const f32x2*)(pp + 48));
            #pragma unroll
            for (int jj = 1; jj < 8; jj++) {
                f32x2 sl = *(const f32x2*)(pp + 32 + 2 * jj);
                f32x2 of = *(const f32x2*)(pp + 48 + 2 * jj);
                #pragma unroll
                for (int r = 0; r < 4; r++)
                    ccv[r] = __builtin_elementwise_min(ccv[r], __builtin_elementwise_fma(z2[r], sl, of));
            }
            #pragma unroll
            for (int r = 0; r < 4; r++) {
                f32x2 tv = __builtin_elementwise_fma(s2, cvx[r] - ccv[r], ccv[r]);
                f32x2 cpre; cpre.x = accc[mi][0][r]; cpre.y = accc[mi][1][r]; cpre += bc2;
                f32x2 gpre; gpre.x = accg[mi][0][r]; gpre.y = accg[mi][1][r]; gpre += bg2;
                float g0 = sigm(gpre.x), g1 = sigm(gpre.y);
                float c0 = gelu_f(cpre.x), c1 = gelu_f(cpre.y);
                float o0 = fmaf(g0, tv.x - c0, c0);
                float o1 = fmaf(g1, tv.y - c1, c1);
                int o = wm * 32 + mi2 * 16 + quad * 4 + r;
                obuf[o * OSTR + wn * 32 + lr]      = f2bf(o0);
                obuf[o * OSTR + wn * 32 + lr + 16] = f2bf(o1);
            }
        }
        __syncthreads();   // half-tile obuf complete
        for (int e = t; e < 64 * 16; e += 512) {
            int o = e >> 4, c8 = (e & 15) << 3;
            ushort8 v = *(const ushort8*)&obuf[o * OSTR + c8];
            int ml = (o >> 5) * 64 + h * 32 + (o & 31);
            *(ushort8*)&fused[(size_t)(bm * 128 + ml) * NF + bf * 128 + c8] = v;
        }
        __syncthreads();   // store reads done before next half overwrites
    }
}

// ------------------------------------------------- kernel 5: GEMM2 (fused@Wd + bd)
// BK=64, 16 K-iters. XCD swizzle: the 2 bn-siblings of a bm consecutive per XCD.
#define LDS2 64
__global__ __launch_bounds__(512, 4) void gemm2_kernel(
    const unsigned short* __restrict__ A,  // fused [T][1024]
    const unsigned short* __restrict__ Bt, // WdT [256][1024]
    const float* __restrict__ bd, float* __restrict__ out) {
    __shared__ __align__(16) unsigned short As[128 * LDS2];
    __shared__ __align__(16) unsigned short Bs[128 * LDS2];
    const int t = threadIdx.x;
    const int b = blockIdx.x;
    const int xcd = b & 7, j = b >> 3;
    const int bn = j & 1;
    const int bm = (j >> 1) * 8 + xcd;
    const int wave = t >> 6, lane = t & 63;
    const int wm = wave & 1, wn = wave >> 1;
    const int lr = lane & 15, quad = lane >> 4;
    const int srow = wave * 8 + (lane >> 3), scol = (lane & 7) << 3;  // 64 rows/issue
    const unsigned short* gA = A  + (size_t)(bm * 128 + srow) * NF + scol;
    const unsigned short* gB = Bt + (size_t)(bn * 128 + srow) * NF + scol;
    unsigned short* lA = &As[wave * 8 * LDS2];
    unsigned short* lB = &Bs[wave * 8 * LDS2];

    floatx4 acc[4][2];
    #pragma unroll
    for (int i = 0; i < 4; i++)
        #pragma unroll
        for (int jj = 0; jj < 2; jj++) acc[i][jj] = (floatx4)0.0f;

    for (int k0 = 0; k0 < NF; k0 += 64) {
        __syncthreads();
        g2lds16(gA + k0, lA);
        g2lds16(gA + k0 + (size_t)64 * NF, lA + 64 * LDS2);
        g2lds16(gB + k0, lB);
        g2lds16(gB + k0 + (size_t)64 * NF, lB + 64 * LDS2);
        __syncthreads();
        #pragma unroll
        for (int ks = 0; ks < 2; ks++) {
            bf16x8 af[4], bf_[2];
            #pragma unroll
            for (int mi = 0; mi < 4; mi++)
                af[mi] = *(const bf16x8*)&As[(wm * 64 + mi * 16 + lr) * LDS2 + ks * 32 + quad * 8];
            #pragma unroll
            for (int ni = 0; ni < 2; ni++)
                bf_[ni] = *(const bf16x8*)&Bs[(wn * 32 + ni * 16 + lr) * LDS2 + ks * 32 + quad * 8];
            #pragma unroll
            for (int mi = 0; mi < 4; mi++)
                #pragma unroll
                for (int ni = 0; ni < 2; ni++)
                    acc[mi][ni] = __builtin_amdgcn_mfma_f32_16x16x32_bf16(af[mi], bf_[ni], acc[mi][ni], 0, 0, 0);
        }
    }
    #pragma unroll
    for (int mi = 0; mi < 4; mi++)
        #pragma unroll
        for (int ni = 0; ni < 2; ni++) {
            int n = bn * 128 + wn * 32 + ni * 16 + lr;
            float bdv = bd[n];
            #pragma unroll
            for (int r = 0; r < 4; r++) {
                int m = bm * 128 + wm * 64 + mi * 16 + quad * 4 + r;
                out[m * DM + n] = acc[mi][ni][r] + bdv;
            }
        }
}

// ------------------------------------------------------------- launcher
extern "C" void kernel_launch(void* const* d_in, const int* in_sizes, int n_in,
                              void* d_out, int out_size, void* d_ws, size_t ws_size,
                              hipStream_t stream) {
    const float* x     = (const float*)d_in[0];
    const float* Wt    = (const float*)d_in[1];
    const float* bt    = (const float*)d_in[2];
    const float* slx   = (const float*)d_in[3];
    const float* ofx   = (const float*)d_in[4];
    const float* slc   = (const float*)d_in[5];
    const float* ofc   = (const float*)d_in[6];
    const float* alpha = (const float*)d_in[7];
    const float* Wc    = (const float*)d_in[8];
    const float* bc    = (const float*)d_in[9];
    const float* Wg    = (const float*)d_in[10];
    const float* bg    = (const float*)d_in[11];
    const float* Wd    = (const float*)d_in[12];
    const float* bd    = (const float*)d_in[13];
    float* out = (float*)d_out;
    char* ws = (char*)d_ws;

    unsigned int* slot = (unsigned int*)(ws + O_SLOT);
    float* s           = (float*)(ws + O_S);
    unsigned short* Wct = (unsigned short*)(ws + O_WCT);
    unsigned short* Wgt = (unsigned short*)(ws + O_WGT);
    unsigned short* WdT = (unsigned short*)(ws + O_WDT);
    float* WtT          = (float*)(ws + O_WTT);
    unsigned short* xbf = (unsigned short*)(ws + O_XBF);
    int* counts         = (int*)(ws + O_CNT);
    int* cidx           = (int*)(ws + O_CIDX);
    float* cval         = (float*)(ws + O_CVAL);
    unsigned short* fused = (unsigned short*)(ws + O_FUSD);

    pack_kernel<<<1024, 256, 0, stream>>>(Wt, alpha, Wc, Wg, Wd, Wct, Wgt, WdT, WtT, s, slot);
    minmax_kernel<<<128, 256, 0, stream>>>(Wt, slot);
    cand_kernel<<<TTOK / 4, 256, 0, stream>>>(x, slot, xbf, counts, cidx, cval);
    gemm1_kernel<<<2048, 512, 0, stream>>>(
        xbf, Wct, Wgt, bc, bg, counts, cidx, cval, x, WtT, bt,
        slx, ofx, slc, ofc, s, fused);
    gemm2_kernel<<<512, 512, 0, stream>>>(fused, WdT, bd, out);
}

// Round 9
// 299.342 us; speedup vs baseline: 1.5037x; 1.5037x over previous
//
#include <hip/hip_runtime.h>

// ---------------------------------------------------------------- constants
#define TTOK 32768
#define DM   256
#define NF   1024
#define KMAX 32

typedef __attribute__((ext_vector_type(8))) unsigned short ushort8;
typedef __attribute__((ext_vector_type(8))) __bf16 bf16x8;
typedef __attribute__((ext_vector_type(4))) float floatx4;
typedef __attribute__((ext_vector_type(2))) float f32x2;

// workspace offsets (all 256B aligned)
constexpr size_t O_SLOT = 0;                                   // 1 uint (max|Wt|)
constexpr size_t O_S    = 256;                                 // 1024 f32 sigmoid(alpha)
constexpr size_t O_WCT  = O_S    + 4096;                       // Wc^T  [1024][256] bf16
constexpr size_t O_WGT  = O_WCT  + (size_t)NF*DM*2;            // Wg^T  [1024][256] bf16
constexpr size_t O_WDT  = O_WGT  + (size_t)NF*DM*2;            // Wd^T  [256][1024] bf16
constexpr size_t O_WTT  = O_WDT  + (size_t)DM*NF*2;            // Wt^T  [256][1024] f32
constexpr size_t O_XBF  = O_WTT  + (size_t)DM*NF*4;            // x bf16 [T][256]
constexpr size_t O_CNT  = O_XBF  + (size_t)TTOK*DM*2;          // counts [T]
constexpr size_t O_CIDX = O_CNT  + (size_t)TTOK*4;             // cand d (raw) [T][KMAX]
constexpr size_t O_CVAL = O_CIDX + (size_t)TTOK*KMAX*4;        // cand val [T][KMAX]
constexpr size_t O_FUSD = O_CVAL + (size_t)TTOK*KMAX*4;        // fused bf16 [T][1024]

__device__ __forceinline__ float bf2f(unsigned short u) {
    union { unsigned int i; float f; } c; c.i = ((unsigned int)u) << 16; return c.f;
}
__device__ __forceinline__ unsigned short f2bf(float v) {
    union { float f; unsigned int i; } c; c.f = v;
    unsigned int b = c.i;
    return (unsigned short)((b + 0x7FFFu + ((b >> 16) & 1u)) >> 16);
}
__device__ __forceinline__ float sigm(float z) { return 1.0f / (1.0f + __expf(-z)); }
// tanh-gelu: max |diff| vs exact erf-gelu ~3e-3, far under 0.266 tolerance
__device__ __forceinline__ float gelu_f(float x) {
    return x * sigm(1.59576912f * (x + 0.044715f * x * x * x));
}
// async global->LDS, 16B per lane; lds dest = wave-uniform base + lane*16 [m97/m104]
__device__ __forceinline__ void g2lds16(const unsigned short* g, unsigned short* l) {
    __builtin_amdgcn_global_load_lds((const __attribute__((address_space(1))) unsigned int*)g,
                                     (__attribute__((address_space(3))) unsigned int*)l, 16, 0, 0);
}

// ------------------------------------------------- kernel 1: pack weights
__global__ void pack_kernel(const float* __restrict__ Wt, const float* __restrict__ alpha,
                            const float* __restrict__ Wc, const float* __restrict__ Wg,
                            const float* __restrict__ Wd,
                            unsigned short* __restrict__ Wct, unsigned short* __restrict__ Wgt,
                            unsigned short* __restrict__ WdT, float* __restrict__ WtT,
                            float* __restrict__ s, unsigned int* __restrict__ slot) {
    int e = blockIdx.x * 256 + threadIdx.x;
    if (e == 0) *slot = 0u;
    { int f = e >> 8, k = e & 255;           // Wc/Wg are [256][1024]
      Wct[e] = f2bf(Wc[k * NF + f]);
      Wgt[e] = f2bf(Wg[k * NF + f]); }
    { int n = e >> 10, k = e & 1023;         // Wd is [1024][256]
      WdT[e] = f2bf(Wd[k * DM + n]); }
    { int d = e >> 10, f = e & 1023;         // Wt is [1024][256]
      WtT[e] = Wt[f * DM + d]; }
    if (e < NF) s[e] = sigm(alpha[e]);
}

// ------------------------------------------------- kernel 2: max|Wt| reduce
__global__ void minmax_kernel(const float* __restrict__ Wt, unsigned int* __restrict__ slot) {
    int g = blockIdx.x * 256 + threadIdx.x;
    float lm = 0.0f;
    for (int i = g; i < NF * DM; i += 128 * 256) lm = fmaxf(lm, fabsf(Wt[i]));
    #pragma unroll
    for (int o = 32; o > 0; o >>= 1) lm = fmaxf(lm, __shfl_xor(lm, o));
    if ((threadIdx.x & 63) == 0) atomicMax(slot, __float_as_uint(lm)); // |w|>=0: uint order ok
}

// ------------------------------------------------- kernel 3: candidates + x->bf16
// wave per token, ballot compaction, no LDS/atomics. lane covers 4 d's.
__global__ void cand_kernel(const float* __restrict__ x, const unsigned int* __restrict__ slot,
                            unsigned short* __restrict__ xbf, int* __restrict__ counts,
                            int* __restrict__ cidx, float* __restrict__ cval) {
    const int wave = threadIdx.x >> 6, lane = threadIdx.x & 63;
    const int i = blockIdx.x * 4 + wave;
    float4 xv = *(const float4*)(x + (size_t)i * DM + lane * 4);
    ushort4 xb;
    xb.x = f2bf(xv.x); xb.y = f2bf(xv.y); xb.z = f2bf(xv.z); xb.w = f2bf(xv.w);
    *(ushort4*)(xbf + (size_t)i * DM + lane * 4) = xb;
    float m = fmaxf(fmaxf(xv.x, xv.y), fmaxf(xv.z, xv.w));
    #pragma unroll
    for (int o = 32; o > 0; o >>= 1) m = fmaxf(m, __shfl_xor(m, o));
    float delta = 2.0f * __uint_as_float(*slot);   // >= Wmax - Wmin : exact exclusion bound
    float thr = m - delta;
    unsigned long long ltmask = (1ULL << lane) - 1;   // lanes below me
    int base = 0;
    float vv[4] = { xv.x, xv.y, xv.z, xv.w };
    #pragma unroll
    for (int j = 0; j < 4; j++) {
        bool p = vv[j] >= thr;
        unsigned long long mk = __ballot(p);
        int pos = base + (int)__popcll(mk & ltmask);
        if (p && pos < KMAX) {
            cidx[(size_t)i * KMAX + pos] = lane * 4 + j;
            cval[(size_t)i * KMAX + pos] = vv[j];
        }
        base += (int)__popcll(mk);
    }
    if (lane == 0) counts[i] = base;
}

// ------------------------------------------------- kernel 4: fused GEMM1
// (x@Wc, x@Wg) MFMA + tropical max-plus + convex/concave + gate blend.
// 128x128 tile, BK=32, 512 thr (8 waves 2Mx4F, wave 64x32 dual-output).
// r9 FIX: r8's `for(h)` epilogue loop wasn't unrolled -> mi dynamic ->
// accc/accg demoted to scratch (WRITE 1.14GB, 320us). #pragma unroll makes
// every acc index compile-time. Everything else = r8 structure:
//  - z-phase: wave-per-token, WAVE-UNIFORM exact k-loop, coalesced Wt reads,
//    z -> LDS bf16 (f,f+16) pairs.
//  - packed <2 x float> epilogue (v_pk_fma/max/min_f32), params in LDS.
//  - half-tile obuf, coalesced 256B stores. XCD swizzle (r7-proven).
#define LDSS 32   // ushorts per LDS row, no pad (wave-uniform-base DMA, m104)
#define KPAD 33
#define OSTR 136
__global__ __launch_bounds__(512, 4) void gemm1_kernel(
    const unsigned short* __restrict__ A,   // xbf [T][256]
    const unsigned short* __restrict__ Bct, // [1024][256]
    const unsigned short* __restrict__ Bgt, // [1024][256]
    const float* __restrict__ bc, const float* __restrict__ bg,
    const int* __restrict__ counts, const int* __restrict__ cidx,
    const float* __restrict__ cval, const float* __restrict__ x,
    const float* __restrict__ WtT, const float* __restrict__ bt,
    const float* __restrict__ slx, const float* __restrict__ ofx,
    const float* __restrict__ slc, const float* __restrict__ ofc,
    const float* __restrict__ s, unsigned short* __restrict__ fused) {
    __shared__ __align__(16) char smem[70144];
    unsigned short* As  = (unsigned short*)smem;            // [0, 8K)       K-loop
    unsigned short* Bcs = As + 4096;                        // [8K, 16K)     K-loop
    unsigned short* Bgs = As + 8192;                        // [16K, 24K)    K-loop
    unsigned int* zbuf = (unsigned int*)smem;               // [0, 33280)    post K-loop
    int* sCnt = (int*)(smem + 33280);                       // 512B
    int* sOV  = (int*)(smem + 33792);                       // 16896 (z-phase)
    float* par2 = (float*)(smem + 33792);                   // 18944 (epilogue, overlays sOV)
    unsigned short* obuf = (unsigned short*)(smem + 52736); // 17408 (64x136)
    const int t = threadIdx.x;
    // XCD-aware swizzle: 8 bf-siblings of one bm consecutive within an XCD
    const int b = blockIdx.x;
    const int xcd = b & 7, j = b >> 3;
    const int bf = j & 7;
    const int bm = (j >> 3) * 8 + xcd;
    const int wave = t >> 6, lane = t & 63;
    const int wm = wave & 1, wn = wave >> 1;
    const int lr = lane & 15, quad = lane >> 4;
    const int srow = wave * 16 + (lane >> 2), scol = (lane & 3) << 3;
    const unsigned short* gA = A   + (size_t)(bm * 128 + srow) * DM + scol;
    const unsigned short* gC = Bct + (size_t)(bf * 128 + srow) * DM + scol;
    const unsigned short* gG = Bgt + (size_t)(bf * 128 + srow) * DM + scol;
    unsigned short* lA = &As[wave * 16 * LDSS];
    unsigned short* lC = &Bcs[wave * 16 * LDSS];
    unsigned short* lG = &Bgs[wave * 16 * LDSS];

    if (t < 128) sCnt[t] = counts[bm * 128 + t];

    floatx4 accc[4][2], accg[4][2];
    #pragma unroll
    for (int i = 0; i < 4; i++)
        #pragma unroll
        for (int jj = 0; jj < 2; jj++) { accc[i][jj] = (floatx4)0.0f; accg[i][jj] = (floatx4)0.0f; }

    for (int k0 = 0; k0 < DM; k0 += 32) {
        __syncthreads();            // covers sCnt stage (1st iter) + prior ds_reads
        g2lds16(gA + k0, lA);
        g2lds16(gC + k0, lC);
        g2lds16(gG + k0, lG);
        __syncthreads();
        bf16x8 af[4], bcf[2], bgf[2];
        #pragma unroll
        for (int mi = 0; mi < 4; mi++)
            af[mi] = *(const bf16x8*)&As[(wm * 64 + mi * 16 + lr) * LDSS + quad * 8];
        #pragma unroll
        for (int ni = 0; ni < 2; ni++) {
            bcf[ni] = *(const bf16x8*)&Bcs[(wn * 32 + ni * 16 + lr) * LDSS + quad * 8];
            bgf[ni] = *(const bf16x8*)&Bgs[(wn * 32 + ni * 16 + lr) * LDSS + quad * 8];
        }
        #pragma unroll
        for (int mi = 0; mi < 4; mi++)
            #pragma unroll
            for (int ni = 0; ni < 2; ni++) {
                accc[mi][ni] = __builtin_amdgcn_mfma_f32_16x16x32_bf16(af[mi], bcf[ni], accc[mi][ni], 0, 0, 0);
                accg[mi][ni] = __builtin_amdgcn_mfma_f32_16x16x32_bf16(af[mi], bgf[ni], accg[mi][ni], 0, 0, 0);
            }
    }
    __syncthreads();   // staging bufs dead

    // ---- stage packed candidate meta: (bf16(val)<<16) | d
    const int PADV = (int)(((unsigned int)f2bf(-1e30f)) << 16);
    for (int e = t; e < 128 * KMAX; e += 512) {
        int m = e >> 5, k = e & 31;
        int c = sCnt[m];
        int pk = PADV;
        if (k < (c < KMAX ? c : KMAX)) {
            int d  = cidx[(size_t)(bm * 128 + m) * KMAX + k];
            float v = cval[(size_t)(bm * 128 + m) * KMAX + k];
            pk = (int)(((unsigned int)f2bf(v)) << 16) | d;
        }
        sOV[m * KPAD + k] = pk;
    }
    __syncthreads();

    // ---- z-phase: wave per token, uniform exact k-loop, coalesced Wt reads
    {
        const int fa = bf * 128 + ((lane >> 4) * 32) + (lane & 15);  // pair = (fa, fa+16)
        for (int mm = 0; mm < 16; mm++) {
            int m = wave * 16 + mm;
            int c = sCnt[m];
            float za = -1e30f, zb = -1e30f;
            if (c <= KMAX) {
                int k = 0;
                for (; k + 1 < c; k += 2) {
                    int p0 = sOV[m * KPAD + k];
                    int p1 = sOV[m * KPAD + k + 1];
                    const float* r0 = WtT + ((p0 & 0xFFFF) << 10) + fa;
                    const float* r1 = WtT + ((p1 & 0xFFFF) << 10) + fa;
                    float w0a = r0[0], w0b = r0[16];
                    float w1a = r1[0], w1b = r1[16];
                    float v0 = __int_as_float(p0 & 0xFFFF0000);
                    float v1 = __int_as_float(p1 & 0xFFFF0000);
                    za = fmaxf(za, v0 + w0a); zb = fmaxf(zb, v0 + w0b);
                    za = fmaxf(za, v1 + w1a); zb = fmaxf(zb, v1 + w1b);
                }
                if (k < c) {
                    int p0 = sOV[m * KPAD + k];
                    const float* r0 = WtT + ((p0 & 0xFFFF) << 10) + fa;
                    float v0 = __int_as_float(p0 & 0xFFFF0000);
                    za = fmaxf(za, v0 + r0[0]); zb = fmaxf(zb, v0 + r0[16]);
                }
            } else {  // exact fallback (never expected)
                const float* xr = x + (size_t)(bm * 128 + m) * DM;
                for (int d = 0; d < DM; d++) {
                    float xv = xr[d];
                    const float* r0 = WtT + d * NF + fa;
                    za = fmaxf(za, xv + r0[0]); zb = fmaxf(zb, xv + r0[16]);
                }
            }
            zbuf[m * 65 + lane] = ((unsigned int)f2bf(zb) << 16) | f2bf(za);
        }
    }
    __syncthreads();

    // ---- stage params as (f, f+16) float2 pairs; stride 74 words
    // idx: 0-7 slx, 8-15 ofx, 16-23 slc, 24-31 ofc, 32 bt, 33 s, 34 bc, 35 bg
    for (int e = t; e < 64 * 36; e += 512) {
        int jl2 = e / 36, idx = e % 36;
        int f0 = bf * 128 + ((jl2 >> 4) * 32) + (jl2 & 15);
        float v0, v1;
        if (idx < 8)       { v0 = slx[f0 * 8 + idx];      v1 = slx[(f0 + 16) * 8 + idx]; }
        else if (idx < 16) { v0 = ofx[f0 * 8 + idx - 8];  v1 = ofx[(f0 + 16) * 8 + idx - 8]; }
        else if (idx < 24) { v0 = slc[f0 * 8 + idx - 16]; v1 = slc[(f0 + 16) * 8 + idx - 16]; }
        else if (idx < 32) { v0 = ofc[f0 * 8 + idx - 24]; v1 = ofc[(f0 + 16) * 8 + idx - 24]; }
        else if (idx == 32){ v0 = bt[f0]; v1 = bt[f0 + 16]; }
        else if (idx == 33){ v0 = s[f0];  v1 = s[f0 + 16]; }
        else if (idx == 34){ v0 = bc[f0]; v1 = bc[f0 + 16]; }
        else               { v0 = bg[f0]; v1 = bg[f0 + 16]; }
        par2[jl2 * 74 + idx * 2]     = v0;
        par2[jl2 * 74 + idx * 2 + 1] = v1;
    }
    __syncthreads();

    // ---- packed epilogue (h UNROLLED: acc indices compile-time, r8 lesson) ----
    const int jl = wn * 16 + lr;
    const float* pp = par2 + jl * 74;
    f32x2 bt2 = *(const f32x2*)(pp + 64);
    f32x2 s2  = *(const f32x2*)(pp + 66);
    f32x2 bc2 = *(const f32x2*)(pp + 68);
    f32x2 bg2 = *(const f32x2*)(pp + 70);
    #pragma unroll
    for (int h = 0; h < 2; h++) {
        #pragma unroll
        for (int mi2 = 0; mi2 < 2; mi2++) {
            const int mi = h * 2 + mi2;
            const int mb = wm * 64 + mi * 16 + quad * 4;
            f32x2 z2[4];
            #pragma unroll
            for (int r = 0; r < 4; r++) {
                unsigned int u = zbuf[(mb + r) * 65 + jl];
                f32x2 zz;
                zz.x = bf2f((unsigned short)(u & 0xFFFF));
                zz.y = bf2f((unsigned short)(u >> 16));
                z2[r] = zz + bt2;
            }
            f32x2 cvx[4], ccv[4];
            #pragma unroll
            for (int r = 0; r < 4; r++)
                cvx[r] = __builtin_elementwise_fma(z2[r], *(const f32x2*)(pp + 0), *(const f32x2*)(pp + 16));
            #pragma unroll
            for (int jj = 1; jj < 8; jj++) {
                f32x2 sl = *(const f32x2*)(pp + 2 * jj);
                f32x2 of = *(const f32x2*)(pp + 16 + 2 * jj);
                #pragma unroll
                for (int r = 0; r < 4; r++)
                    cvx[r] = __builtin_elementwise_max(cvx[r], __builtin_elementwise_fma(z2[r], sl, of));
            }
            #pragma unroll
            for (int r = 0; r < 4; r++)
                ccv[r] = __builtin_elementwise_fma(z2[r], *(const f32x2*)(pp + 32), *(const f32x2*)(pp + 48));
            #pragma unroll
            for (int jj = 1; jj < 8; jj++) {
                f32x2 sl = *(const f32x2*)(pp + 32 + 2 * jj);
                f32x2 of = *(const f32x2*)(pp + 48 + 2 * jj);
                #pragma unroll
                for (int r = 0; r < 4; r++)
                    ccv[r] = __builtin_elementwise_min(ccv[r], __builtin_elementwise_fma(z2[r], sl, of));
            }
            #pragma unroll
            for (int r = 0; r < 4; r++) {
                f32x2 tv = __builtin_elementwise_fma(s2, cvx[r] - ccv[r], ccv[r]);
                f32x2 cpre; cpre.x = accc[mi][0][r]; cpre.y = accc[mi][1][r]; cpre += bc2;
                f32x2 gpre; gpre.x = accg[mi][0][r]; gpre.y = accg[mi][1][r]; gpre += bg2;
                float g0 = sigm(gpre.x), g1 = sigm(gpre.y);
                float c0 = gelu_f(cpre.x), c1 = gelu_f(cpre.y);
                float o0 = fmaf(g0, tv.x - c0, c0);
                float o1 = fmaf(g1, tv.y - c1, c1);
                int o = wm * 32 + mi2 * 16 + quad * 4 + r;
                obuf[o * OSTR + wn * 32 + lr]      = f2bf(o0);
                obuf[o * OSTR + wn * 32 + lr + 16] = f2bf(o1);
            }
        }
        __syncthreads();   // half-tile obuf complete
        for (int e = t; e < 64 * 16; e += 512) {
            int o = e >> 4, c8 = (e & 15) << 3;
            ushort8 v = *(const ushort8*)&obuf[o * OSTR + c8];
            int ml = (o >> 5) * 64 + h * 32 + (o & 31);
            *(ushort8*)&fused[(size_t)(bm * 128 + ml) * NF + bf * 128 + c8] = v;
        }
        __syncthreads();   // store reads done before next half overwrites
    }
}

// ------------------------------------------------- kernel 5: GEMM2 (fused@Wd + bd)
// BK=64, 16 K-iters. XCD swizzle: the 2 bn-siblings of a bm consecutive per XCD.
#define LDS2 64
__global__ __launch_bounds__(512, 4) void gemm2_kernel(
    const unsigned short* __restrict__ A,  // fused [T][1024]
    const unsigned short* __restrict__ Bt, // WdT [256][1024]
    const float* __restrict__ bd, float* __restrict__ out) {
    __shared__ __align__(16) unsigned short As[128 * LDS2];
    __shared__ __align__(16) unsigned short Bs[128 * LDS2];
    const int t = threadIdx.x;
    const int b = blockIdx.x;
    const int xcd = b & 7, j = b >> 3;
    const int bn = j & 1;
    const int bm = (j >> 1) * 8 + xcd;
    const int wave = t >> 6, lane = t & 63;
    const int wm = wave & 1, wn = wave >> 1;
    const int lr = lane & 15, quad = lane >> 4;
    const int srow = wave * 8 + (lane >> 3), scol = (lane & 7) << 3;  // 64 rows/issue
    const unsigned short* gA = A  + (size_t)(bm * 128 + srow) * NF + scol;
    const unsigned short* gB = Bt + (size_t)(bn * 128 + srow) * NF + scol;
    unsigned short* lA = &As[wave * 8 * LDS2];
    unsigned short* lB = &Bs[wave * 8 * LDS2];

    floatx4 acc[4][2];
    #pragma unroll
    for (int i = 0; i < 4; i++)
        #pragma unroll
        for (int jj = 0; jj < 2; jj++) acc[i][jj] = (floatx4)0.0f;

    for (int k0 = 0; k0 < NF; k0 += 64) {
        __syncthreads();
        g2lds16(gA + k0, lA);
        g2lds16(gA + k0 + (size_t)64 * NF, lA + 64 * LDS2);
        g2lds16(gB + k0, lB);
        g2lds16(gB + k0 + (size_t)64 * NF, lB + 64 * LDS2);
        __syncthreads();
        #pragma unroll
        for (int ks = 0; ks < 2; ks++) {
            bf16x8 af[4], bf_[2];
            #pragma unroll
            for (int mi = 0; mi < 4; mi++)
                af[mi] = *(const bf16x8*)&As[(wm * 64 + mi * 16 + lr) * LDS2 + ks * 32 + quad * 8];
            #pragma unroll
            for (int ni = 0; ni < 2; ni++)
                bf_[ni] = *(const bf16x8*)&Bs[(wn * 32 + ni * 16 + lr) * LDS2 + ks * 32 + quad * 8];
            #pragma unroll
            for (int mi = 0; mi < 4; mi++)
                #pragma unroll
                for (int ni = 0; ni < 2; ni++)
                    acc[mi][ni] = __builtin_amdgcn_mfma_f32_16x16x32_bf16(af[mi], bf_[ni], acc[mi][ni], 0, 0, 0);
        }
    }
    #pragma unroll
    for (int mi = 0; mi < 4; mi++)
        #pragma unroll
        for (int ni = 0; ni < 2; ni++) {
            int n = bn * 128 + wn * 32 + ni * 16 + lr;
            float bdv = bd[n];
            #pragma unroll
            for (int r = 0; r < 4; r++) {
                int m = bm * 128 + wm * 64 + mi * 16 + quad * 4 + r;
                out[m * DM + n] = acc[mi][ni][r] + bdv;
            }
        }
}

// ------------------------------------------------------------- launcher
extern "C" void kernel_launch(void* const* d_in, const int* in_sizes, int n_in,
                              void* d_out, int out_size, void* d_ws, size_t ws_size,
                              hipStream_t stream) {
    const float* x     = (const float*)d_in[0];
    const float* Wt    = (const float*)d_in[1];
    const float* bt    = (const float*)d_in[2];
    const float* slx   = (const float*)d_in[3];
    const float* ofx   = (const float*)d_in[4];
    const float* slc   = (const float*)d_in[5];
    const float* ofc   = (const float*)d_in[6];
    const float* alpha = (const float*)d_in[7];
    const float* Wc    = (const float*)d_in[8];
    const float* bc    = (const float*)d_in[9];
    const float* Wg    = (const float*)d_in[10];
    const float* bg    = (const float*)d_in[11];
    const float* Wd    = (const float*)d_in[12];
    const float* bd    = (const float*)d_in[13];
    float* out = (float*)d_out;
    char* ws = (char*)d_ws;

    unsigned int* slot = (unsigned int*)(ws + O_SLOT);
    float* s           = (float*)(ws + O_S);
    unsigned short* Wct = (unsigned short*)(ws + O_WCT);
    unsigned short* Wgt = (unsigned short*)(ws + O_WGT);
    unsigned short* WdT = (unsigned short*)(ws + O_WDT);
    float* WtT          = (float*)(ws + O_WTT);
    unsigned short* xbf = (unsigned short*)(ws + O_XBF);
    int* counts         = (int*)(ws + O_CNT);
    int* cidx           = (int*)(ws + O_CIDX);
    float* cval         = (float*)(ws + O_CVAL);
    unsigned short* fused = (unsigned short*)(ws + O_FUSD);

    pack_kernel<<<1024, 256, 0, stream>>>(Wt, alpha, Wc, Wg, Wd, Wct, Wgt, WdT, WtT, s, slot);
    minmax_kernel<<<128, 256, 0, stream>>>(Wt, slot);
    cand_kernel<<<TTOK / 4, 256, 0, stream>>>(x, slot, xbf, counts, cidx, cval);
    gemm1_kernel<<<2048, 512, 0, stream>>>(
        xbf, Wct, Wgt, bc, bg, counts, cidx, cval, x, WtT, bt,
        slx, ofx, slc, ofc, s, fused);
    gemm2_kernel<<<512, 512, 0, stream>>>(fused, WdT, bd, out);
}